// Round 11
// baseline (165.956 us; speedup 1.0000x reference)
//
#include <hip/hip_runtime.h>
#include <hip/hip_bf16.h>

#define N_B   16
#define CIO   512
#define LSEQ  384
#define DH    64
#define NH    8
#define CHID  512
#define ME    384

typedef __hip_bfloat16 bf16;
typedef __attribute__((ext_vector_type(8))) short bf16x8;
typedef __attribute__((ext_vector_type(4))) float f32x4;

#define AS1 __attribute__((address_space(1)))
#define AS3 __attribute__((address_space(3)))

__device__ __forceinline__ unsigned short f2bs(float f) {
    union { bf16 b; unsigned short u; } cv; cv.b = __float2bfloat16(f); return cv.u;
}

// async 16B global->LDS: lds dest = wave-uniform base + lane*16
__device__ __forceinline__ void gload_lds16(const bf16* g, bf16* l) {
    __builtin_amdgcn_global_load_lds((const AS1 unsigned int*)g,
                                     (AS3 unsigned int*)l, 16, 0, 0);
}

// raw s_barrier WITH compiler memory fence (no vmcnt drain at ISA level).
// R9 lesson: __builtin_amdgcn_s_barrier() is IntrNoMem -> hipcc hoists
// LDS-writing DMA across it -> race. asm+memory clobber = fence + barrier.
__device__ __forceinline__ void barrier_fenced() {
    asm volatile("s_barrier" ::: "memory");
}

// ---------------------------------------------------------------------------
// prep (+ folded wconv): X1/X0 rezero -> bf16 transposed [n][l][c]; gate
// partials into gpart; first 512 flat-id blocks also convert weight chunks.
// (unchanged from R5/R6/R7)
// ---------------------------------------------------------------------------
__launch_bounds__(256)
__global__ void prep_kernel(const float* __restrict__ x, const float* __restrict__ xorg,
                            const float* __restrict__ abspos,
                            const float* __restrict__ qkorg, const float* __restrict__ qkpos,
                            const float* __restrict__ vorg,
                            const float* __restrict__ gw,
                            const float* __restrict__ q_w, const float* __restrict__ k_w,
                            const float* __restrict__ v_w, const float* __restrict__ dense_w,
                            bf16* __restrict__ wqb, bf16* __restrict__ wkb,
                            bf16* __restrict__ wvb, bf16* __restrict__ wdb,
                            bf16* __restrict__ x1t, bf16* __restrict__ x0t,
                            float* __restrict__ gpart)
{
    __shared__ bf16 T1[64 * 72], T0[64 * 72];
    __shared__ float Traw[64 * 65];
    __shared__ float gws[NH * 64];
    __shared__ float r0[64], r1[64], r2[64];
    const int tid = threadIdx.x;
    const int cb = blockIdx.x;
    const int c0 = cb * 64;
    const int l0 = blockIdx.y * 64;
    const int n  = blockIdx.z;

    {
        int f = blockIdx.x + 8 * (blockIdx.y + 6 * blockIdx.z);
        if (f < 512) {
            int e = (f * 256 + tid) * 8;
            int which = e >> 18;
            int off = e & ((1 << 18) - 1);
            const float* s = which == 0 ? q_w : which == 1 ? k_w : which == 2 ? v_w : dense_w;
            bf16* d       = which == 0 ? wqb : which == 1 ? wkb : which == 2 ? wvb : wdb;
            float4 f0 = *(const float4*)&s[off];
            float4 f1 = *(const float4*)&s[off + 4];
            unsigned short u[8] = {f2bs(f0.x), f2bs(f0.y), f2bs(f0.z), f2bs(f0.w),
                                   f2bs(f1.x), f2bs(f1.y), f2bs(f1.z), f2bs(f1.w)};
            *(uint4*)&d[off] = *(uint4*)u;
        }
    }

    if (tid < 64) {
        int gidx = (c0 + tid) >> 3;
        r0[tid] = vorg[gidx];
        r1[tid] = qkorg[gidx];
        r2[tid] = qkpos[gidx];
    }
    for (int t = tid; t < NH * 64; t += 256) {
        int h = t >> 6, c = t & 63;
        gws[t] = gw[h * CIO + c0 + c];
    }
    __syncthreads();
    const int l = tid & 63, cs = tid >> 6;
    #pragma unroll
    for (int r = 0; r < 16; r++) {
        int cl = r * 4 + cs;
        size_t gi = ((size_t)n * CIO + c0 + cl) * LSEQ + l0 + l;
        float xv = x[gi], xo = xorg[gi];
        Traw[cl * 65 + l] = xv;
        T0[l * 72 + cl] = __float2bfloat16(xv + r0[cl] * xo);
        T1[l * 72 + cl] = __float2bfloat16(xv + r1[cl] * xo + r2[cl] * abspos[gi]);
    }
    __syncthreads();
    for (int t = tid; t < NH * 64; t += 256) {
        int h = t >> 6, ll = t & 63;
        float s = 0.f;
        #pragma unroll
        for (int c = 0; c < 64; c++) s += gws[h * 64 + c] * Traw[c * 65 + ll];
        gpart[(((size_t)cb * N_B + n) * NH + h) * LSEQ + l0 + ll] = s;
    }
    #pragma unroll
    for (int t = 0; t < 2; t++) {
        int idx = t * 256 + tid;
        int lr = idx >> 3, u = idx & 7;
        size_t go = ((size_t)n * LSEQ + l0 + lr) * CIO + c0 + u * 8;
        *(uint4*)&x1t[go] = *(const uint4*)&T1[lr * 72 + u * 8];
        *(uint4*)&x0t[go] = *(const uint4*)&T0[lr * 72 + u * 8];
    }
}

// ---------------------------------------------------------------------------
// Staged MFMA GEMM for q/k/v. R11: counted-vmcnt DOUBLE-BUFFERED K-loop at
// BK=32 (LDS stays 32KB -> occupancy unchanged vs R6/R7; m132: 64KB would
// halve blocks/CU). R3's dbuf test was confounded: __syncthreads drains
// vmcnt(0), killing the prefetch. Now (R10-proven pattern): stage(it+1) ->
// vmcnt(4) [tile it resident, it+1's 4 loads stay live] -> fenced B1 ->
// ds_read + 16 MFMA -> fenced B2 (no drain; protects buf cur^1 from
// it+1's stage). Staging addresses = R2's proven BK=32 coords.
// Grid 576 = 12 ot x 3 lt x 16 n, n = Bid&7 (+8).
// ot 0..3: q (trans out), 4..7: k (trans out), 8..11: v (natural out).
// ---------------------------------------------------------------------------
__launch_bounds__(256)
__global__ void qkv_kernel(const bf16* __restrict__ wall,
                           const bf16* __restrict__ x1t, const bf16* __restrict__ x0t,
                           bf16* __restrict__ qb, bf16* __restrict__ kb,
                           bf16* __restrict__ vb)
{
    __shared__ __align__(16) char smem[32768];
    bf16* As = (bf16*)smem;             // [2][128][32]
    bf16* Bs = (bf16*)(smem + 16384);   // [2][128][32]
    bf16* S  = (bf16*)smem;             // epilogue [64][136]

    const int tid = threadIdx.x;
    const int lane = tid & 63, w = tid >> 6;
    const int l15 = lane & 15, g = lane >> 4;
    const int Bid = blockIdx.x;
    const int rres = Bid & 7, qq = Bid >> 3;    // 0..71
    const int n = rres + 8 * (qq / 36);
    const int t = qq % 36;
    const int ot = t / 3;          // 0..11
    const int lt = t % 3;
    const int osub = (w & 1) * 64, lsub = (w >> 1) * 64;

    const bf16* Wt = wall + (size_t)(ot * 128) * CIO;
    const bf16* Bt = (ot < 8 ? x1t : x0t) + ((size_t)n * LSEQ + lt * 128) * CIO;

    // staging coords (R2): wave w stages segs {2w,2w+1} of A and of B.
    // seg*1024B, lane covers bytes [lane*16): elem e = seg*512 + lane*8
    const int segA = 2 * w, segB = 2 * w + 1;
    const int eA = segA * 512 + lane * 8;
    const int eB = segB * 512 + lane * 8;
    const int rA = eA >> 5, cA = eA & 31;
    const int rB = eB >> 5, cB = eB & 31;

    f32x4 acc[4][4];
    #pragma unroll
    for (int mt = 0; mt < 4; mt++)
        #pragma unroll
        for (int jt = 0; jt < 4; jt++) acc[mt][jt] = f32x4{0.f, 0.f, 0.f, 0.f};

    // prologue: stage K-step 0 into buf 0
    gload_lds16(Wt + (size_t)rA * CIO + cA, As + segA * 512);
    gload_lds16(Wt + (size_t)rB * CIO + cB, As + segB * 512);
    gload_lds16(Bt + (size_t)rA * CIO + cA, Bs + segA * 512);
    gload_lds16(Bt + (size_t)rB * CIO + cB, Bs + segB * 512);

    #pragma unroll 2
    for (int it = 0; it < 16; ++it) {
        const int cur = it & 1;
        if (it < 15) {
            const int k1 = (it + 1) * 32;
            bf16* Ad = As + (cur ^ 1) * 4096;
            bf16* Bd = Bs + (cur ^ 1) * 4096;
            gload_lds16(Wt + (size_t)rA * CIO + k1 + cA, Ad + segA * 512);
            gload_lds16(Wt + (size_t)rB * CIO + k1 + cB, Ad + segB * 512);
            gload_lds16(Bt + (size_t)rA * CIO + k1 + cA, Bd + segA * 512);
            gload_lds16(Bt + (size_t)rB * CIO + k1 + cB, Bd + segB * 512);
            // wait for tile it's 4 loads (issued last iter); keep it+1's live
            asm volatile("s_waitcnt vmcnt(4)" ::: "memory");
        } else {
            asm volatile("s_waitcnt vmcnt(0)" ::: "memory");
        }
        __builtin_amdgcn_sched_barrier(0);
        barrier_fenced();   // B1: all waves' tile-it chunks resident (fenced)

        const bf16* Ac = As + cur * 4096;
        const bf16* Bc = Bs + cur * 4096;
        bf16x8 af[4], bfv[4];
        #pragma unroll
        for (int mt = 0; mt < 4; mt++)
            af[mt] = *(const bf16x8*)&Ac[(osub + mt * 16 + l15) * 32 + 8 * g];
        #pragma unroll
        for (int jt = 0; jt < 4; jt++)
            bfv[jt] = *(const bf16x8*)&Bc[(lsub + jt * 16 + l15) * 32 + 8 * g];
        #pragma unroll
        for (int mt = 0; mt < 4; mt++)
            #pragma unroll
            for (int jt = 0; jt < 4; jt++)
                acc[mt][jt] = __builtin_amdgcn_mfma_f32_16x16x32_bf16(af[mt], bfv[jt], acc[mt][jt], 0, 0, 0);

        barrier_fenced();   // B2: reads of buf cur done; no drain (fenced)
    }

    // lane holds C[o = osub+mt*16+4g+r][l = lsub+jt*16+l15]
    if (ot < 8) {
        // q/k: transposed out [n][h][l][d], h = 2*(ot&3) + (o>>6)
        bf16* dstb = (ot < 4) ? qb : kb;
        const int hbase = 2 * (ot & 3);
        #pragma unroll
        for (int lh = 0; lh < 2; ++lh) {
            if ((w >> 1) == lh) {
                #pragma unroll
                for (int mt = 0; mt < 4; mt++)
                    #pragma unroll
                    for (int jt = 0; jt < 4; jt++)
                        #pragma unroll
                        for (int r = 0; r < 4; r++)
                            S[(jt * 16 + l15) * 136 + osub + mt * 16 + 4 * g + r] =
                                __float2bfloat16(acc[mt][jt][r]);
            }
            __syncthreads();
            #pragma unroll
            for (int t2 = 0; t2 < 4; ++t2) {
                int idx = t2 * 256 + tid;          // 0..1023
                int lr = idx >> 4, u = idx & 15;
                int ho = u >> 3, dc = u & 7;
                bf16* dst = dstb + (((size_t)n * NH + hbase + ho) * LSEQ
                                    + lt * 128 + lh * 64 + lr) * DH + dc * 8;
                *(uint4*)dst = *(const uint4*)&S[lr * 136 + u * 8];
            }
            __syncthreads();
        }
    } else {
        // v: natural [n][o][l]
        const int ob = (ot - 8) * 128;
        #pragma unroll
        for (int oh = 0; oh < 2; ++oh) {
            if ((w & 1) == oh) {
                #pragma unroll
                for (int mt = 0; mt < 4; mt++)
                    #pragma unroll
                    for (int jt = 0; jt < 4; jt++)
                        #pragma unroll
                        for (int r = 0; r < 4; r++)
                            S[(mt * 16 + 4 * g + r) * 136 + lsub + jt * 16 + l15] =
                                __float2bfloat16(acc[mt][jt][r]);
            }
            __syncthreads();
            #pragma unroll
            for (int t2 = 0; t2 < 4; ++t2) {
                int idx = t2 * 256 + tid;
                int orr = idx >> 4, u = idx & 15;
                bf16* dst = vb + ((size_t)(n * CHID + ob + oh * 64 + orr)) * LSEQ
                               + lt * 128 + u * 8;
                *(uint4*)dst = *(const uint4*)&S[orr * 136 + u * 8];
            }
            __syncthreads();
        }
    }
}

// ---------------------------------------------------------------------------
// MFMA attention v3 (R7 form — best measured): flash-style over 6 KV-tiles
// of 64, K/V staged via global_load_lds, double-buffered, 1 __syncthreads
// per tile, XOR-swizzled. Online softmax. R8 (2x QBLK) and R10 (counted
// vmcnt) were both neutral -> attn's prefetch is covered by inter-block TLP
// (3 blocks/CU); keep the simplest proven form.
// ---------------------------------------------------------------------------
#define KVT 64
#define NT  (LSEQ / KVT)

__launch_bounds__(256, 3)
__global__ void attn_kernel(const bf16* __restrict__ qt,
                            const bf16* __restrict__ kt,
                            const bf16* __restrict__ v,
                            const float* __restrict__ gpart,
                            const float* __restrict__ gb,
                            const float* __restrict__ mask,
                            const float* __restrict__ norm,
                            const float* __restrict__ relpos,
                            bf16* __restrict__ ctxt)
{
    __shared__ __align__(16) bf16 Kb[2][KVT * DH];   // 2 x 8KB
    __shared__ __align__(16) bf16 Vb[2][KVT * DH];   // 2 x 8KB
    __shared__ __align__(16) bf16 P[4 * 16 * 64];    // 8KB, wave-private 16x64
    __shared__ float relp_s[2 * ME - 1];
    __shared__ float radd_s[LSEQ];

    const int tid = threadIdx.x;
    const int Bid = blockIdx.x;
    const int rres = Bid & 7, qq = Bid >> 3;
    const int n = rres + 8 * (qq / 48);
    const int rem = qq % 48;
    const int h = rem / 6;
    const int i0 = (rem % 6) * 64;
    const int lane = tid & 63;
    const int w = tid >> 6;
    const int l15 = lane & 15, g = lane >> 4;
    const int m0 = w * 16;

    const size_t nh = (size_t)n * NH + h;
    const bf16* kt_g = kt + nh * LSEQ * DH;                      // [384][64]
    const bf16* vg   = v + ((size_t)n * CHID + h * DH) * LSEQ;   // [64][384]

    {
        const float gbh = gb[h];
        for (int i = tid; i < LSEQ; i += 256) {
            float s = gbh + mask[(size_t)n * LSEQ + i];
            #pragma unroll
            for (int cb = 0; cb < 8; cb++)
                s += gpart[(((size_t)cb * N_B + n) * NH + h) * LSEQ + i];
            radd_s[i] = s;
        }
    }
    for (int i = tid; i < 2 * ME - 1; i += 256) relp_s[i] = relpos[i];

    const bf16* qrow = qt + (nh * LSEQ + i0 + m0 + l15) * DH;
    bf16x8 a0 = *(const bf16x8*)&qrow[8 * g];
    bf16x8 a1 = *(const bf16x8*)&qrow[8 * g + 32];
    const float inv_norm = 1.0f / norm[n];

    // staging: tile = 8KB = 512 x 16B chunks; wave w covers chunks
    // {2w,2w+1}*64+lane. LDS dest is linear; global source is pre-swizzled:
    // chunk c -> row=c>>3, colchunk=(c&7)^(row&7)  (inverse == forward XOR).
    const int c0_ = (2 * w) * 64 + lane;
    const int c1_ = (2 * w + 1) * 64 + lane;
    const int kr0 = c0_ >> 3, kc0 = ((c0_ & 7) ^ (kr0 & 7)) * 8;
    const int kr1 = c1_ >> 3, kc1 = ((c1_ & 7) ^ (kr1 & 7)) * 8;
    const int koff0 = kr0 * DH + kc0, koff1 = kr1 * DH + kc1;
    const int voff0 = kr0 * LSEQ + kc0, voff1 = kr1 * LSEQ + kc1;

    // prologue: stage tile 0 into buf 0
    gload_lds16(kt_g + koff0, &Kb[0][(2 * w) * 512]);
    gload_lds16(kt_g + koff1, &Kb[0][(2 * w + 1) * 512]);
    gload_lds16(vg + voff0, &Vb[0][(2 * w) * 512]);
    gload_lds16(vg + voff1, &Vb[0][(2 * w + 1) * 512]);
    __syncthreads();   // drains vmcnt -> tile0 resident; radd/relp ready

    const int ib = i0 + m0 + 4 * g;
    bf16* Pw = P + w * 1024;      // wave-private [16][64], XOR-swizzled

    f32x4 oacc[4];
    #pragma unroll
    for (int dn = 0; dn < 4; dn++) oacc[dn] = f32x4{0.f, 0.f, 0.f, 0.f};
    float m_r[4]  = {-1e30f, -1e30f, -1e30f, -1e30f};
    float lsum[4] = {0.f, 0.f, 0.f, 0.f};

    #pragma unroll 2
    for (int t = 0; t < NT; ++t) {
        const int cur = t & 1;
        if (t + 1 < NT) {
            const bf16* kn = kt_g + (t + 1) * (KVT * DH);
            const bf16* vn = vg + (t + 1) * KVT;
            gload_lds16(kn + koff0, &Kb[cur ^ 1][(2 * w) * 512]);
            gload_lds16(kn + koff1, &Kb[cur ^ 1][(2 * w + 1) * 512]);
            gload_lds16(vn + voff0, &Vb[cur ^ 1][(2 * w) * 512]);
            gload_lds16(vn + voff1, &Vb[cur ^ 1][(2 * w + 1) * 512]);
        }

        // ---- QK^T on Kb[cur] (swizzled reads, <=2-way banks) ----
        f32x4 acc[4];
        #pragma unroll
        for (int jt = 0; jt < 4; jt++) acc[jt] = f32x4{0.f, 0.f, 0.f, 0.f};
        #pragma unroll
        for (int jt = 0; jt < 4; jt++) {
            const int row = jt * 16 + l15;
            bf16x8 b0 = *(const bf16x8*)&Kb[cur][row * 64 + ((g ^ (row & 7)) * 8)];
            bf16x8 b1 = *(const bf16x8*)&Kb[cur][row * 64 + (((4 + g) ^ (row & 7)) * 8)];
            acc[jt] = __builtin_amdgcn_mfma_f32_16x16x32_bf16(a0, b0, acc[jt], 0, 0, 0);
            acc[jt] = __builtin_amdgcn_mfma_f32_16x16x32_bf16(a1, b1, acc[jt], 0, 0, 0);
        }

        // ---- scores + tile max ----
        float mx[4] = {-1e30f, -1e30f, -1e30f, -1e30f};
        #pragma unroll
        for (int jt = 0; jt < 4; jt++) {
            const int j = t * KVT + jt * 16 + l15;
            const float ra = radd_s[j];
            const int idxb = ME - ib + j;
            #pragma unroll
            for (int r = 0; r < 4; r++) {
                int idx = idxb - r;
                idx = (idx > 2 * ME - 2) ? (2 * ME - 2) : idx;
                float s = (acc[jt][r] + relp_s[idx] + ra) * inv_norm;
                acc[jt][r] = s;
                mx[r] = fmaxf(mx[r], s);
            }
        }
        // ---- online max update + rescale running state ----
        #pragma unroll
        for (int r = 0; r < 4; r++) {
            #pragma unroll
            for (int off = 1; off <= 8; off <<= 1)
                mx[r] = fmaxf(mx[r], __shfl_xor(mx[r], off));
            float mnew = fmaxf(m_r[r], mx[r]);
            float sc = __expf(m_r[r] - mnew);
            m_r[r] = mnew;
            lsum[r] *= sc;
            #pragma unroll
            for (int dn = 0; dn < 4; dn++) oacc[dn][r] *= sc;
        }
        // ---- exp + P write (unscaled; swizzled) ----
        #pragma unroll
        for (int jt = 0; jt < 4; jt++) {
            const int col = jt * 16 + l15;
            #pragma unroll
            for (int r = 0; r < 4; r++) {
                const int lr = 4 * g + r;
                float e = __expf(acc[jt][r] - m_r[r]);
                lsum[r] += e;
                Pw[lr * 64 + (col ^ ((lr & 7) << 3))] = __float2bfloat16(e);
            }
        }

        // ---- PV on Vb[cur] (P is wave-private: lgkmcnt order, no barrier) ----
        #pragma unroll
        for (int kh = 0; kh < 2; kh++) {
            bf16x8 a = *(const bf16x8*)&Pw[l15 * 64 + (((kh * 4 + g) ^ (l15 & 7)) * 8)];
            #pragma unroll
            for (int dn = 0; dn < 4; dn++) {
                const int vr = dn * 16 + l15;
                bf16x8 bv = *(const bf16x8*)&Vb[cur][vr * 64 + (((kh * 4 + g) ^ (vr & 7)) * 8)];
                oacc[dn] = __builtin_amdgcn_mfma_f32_16x16x32_bf16(a, bv, oacc[dn], 0, 0, 0);
            }
        }
        __syncthreads();   // compute(t) done for all waves + drains t+1 stage
    }

    // ---- final denominator + normalize ----
    float rs[4];
    #pragma unroll
    for (int r = 0; r < 4; r++) {
        float tm = lsum[r];
        #pragma unroll
        for (int off = 1; off <= 8; off <<= 1) tm += __shfl_xor(tm, off);
        rs[r] = 1.0f / tm;
    }

    // epilogue: O through Kb (free after last tile barrier), [64][72]
    bf16* O = &Kb[0][0];
    #pragma unroll
    for (int dn = 0; dn < 4; dn++)
        #pragma unroll
        for (int r = 0; r < 4; r++)
            O[(m0 + 4 * g + r) * 72 + dn * 16 + l15] = __float2bfloat16(oacc[dn][r] * rs[r]);
    __syncthreads();

    bf16* cg_ = ctxt + ((size_t)n * LSEQ + i0) * CHID + h * DH;
    #pragma unroll
    for (int t = 0; t < 2; t++) {
        int idx = t * 256 + tid;
        int ir = idx >> 3, u = idx & 7;
        *(uint4*)&cg_[(size_t)ir * CHID + u * 8] = *(const uint4*)&O[ir * 72 + u * 8];
    }
}

// ---------------------------------------------------------------------------
// Dense GEMM: staged 128x128 tile, BK=64, XOR-swizzled global_load_lds.
// (unchanged from R7)
// ---------------------------------------------------------------------------
__launch_bounds__(256)
__global__ void dense_kernel(const bf16* __restrict__ Wb,
                             const bf16* __restrict__ Bt,
                             const float* __restrict__ bias,
                             float* __restrict__ outf)
{
    __shared__ __align__(16) char smem[32768];
    bf16* As = (bf16*)smem;             // [128][64], XOR-swizzled
    bf16* Bs = (bf16*)(smem + 16384);   // [128][64], XOR-swizzled
    float* Sf = (float*)smem;           // epilogue quadrant [64][68] f32

    const int tid = threadIdx.x;
    const int lane = tid & 63, w = tid >> 6;
    const int l15 = lane & 15, g = lane >> 4;
    const int Bid = blockIdx.x;
    const int rres = Bid & 7, qq = Bid >> 3;    // 0..23
    const int n = rres + 8 * (qq / 12);
    const int t = qq % 12;
    const int ot = t / 3;          // 0..3 -> o0 = ot*128
    const int lt = t % 3;          // l0 = lt*128
    const int o0 = ot * 128, l0 = lt * 128;
    const int osub = (w & 1) * 64, lsub = (w >> 1) * 64;

    const bf16* Wt = Wb + (size_t)o0 * CIO;
    const bf16* Btb = Bt + ((size_t)n * LSEQ + l0) * CIO;

    int crow[4], ccol[4];
    #pragma unroll
    for (int j = 0; j < 4; j++) {
        int c = (w * 4 + j) * 64 + lane;
        crow[j] = c >> 3;
        ccol[j] = ((c & 7) ^ (crow[j] & 7)) * 8;
    }

    f32x4 acc[4][4];
    #pragma unroll
    for (int mt = 0; mt < 4; mt++)
        #pragma unroll
        for (int jt = 0; jt < 4; jt++) acc[mt][jt] = f32x4{0.f, 0.f, 0.f, 0.f};

    const int swl = (l15 & 7);

    for (int it = 0; it < 8; ++it) {
        const int k0 = it * 64;
        #pragma unroll
        for (int j = 0; j < 4; j++) {
            gload_lds16(Wt + (size_t)crow[j] * CIO + k0 + ccol[j], As + (w * 4 + j) * 512);
            gload_lds16(Btb + (size_t)crow[j] * CIO + k0 + ccol[j], Bs + (w * 4 + j) * 512);
        }
        __syncthreads();
        #pragma unroll
        for (int kk = 0; kk < 2; kk++) {
            const int cS = ((kk * 4 + g) ^ swl) * 8;
            bf16x8 af[4], bfv[4];
            #pragma unroll
            for (int mt = 0; mt < 4; mt++)
                af[mt] = *(const bf16x8*)&As[(osub + mt * 16 + l15) * 64 + cS];
            #pragma unroll
            for (int jt = 0; jt < 4; jt++)
                bfv[jt] = *(const bf16x8*)&Bs[(lsub + jt * 16 + l15) * 64 + cS];
            #pragma unroll
            for (int mt = 0; mt < 4; mt++)
                #pragma unroll
                for (int jt = 0; jt < 4; jt++)
                    acc[mt][jt] = __builtin_amdgcn_mfma_f32_16x16x32_bf16(af[mt], bfv[jt], acc[mt][jt], 0, 0, 0);
        }
        __syncthreads();
    }

    // epilogue: quadrant (oh,lh) owned by wave p = oh + 2*lh; 4 passes.
    #pragma unroll
    for (int p = 0; p < 4; ++p) {
        const int oh = p & 1, lh = p >> 1;
        if (w == p) {
            #pragma unroll
            for (int mt = 0; mt < 4; mt++) {
                #pragma unroll
                for (int r = 0; r < 4; r++) {
                    const float bv = bias[o0 + osub + mt * 16 + 4 * g + r];
                    #pragma unroll
                    for (int jt = 0; jt < 4; jt++)
                        Sf[(mt * 16 + 4 * g + r) * 68 + jt * 16 + l15] = acc[mt][jt][r] + bv;
                }
            }
        }
        __syncthreads();
        float* og = outf + ((size_t)n * CHID + o0 + oh * 64) * LSEQ + l0 + lh * 64;
        #pragma unroll
        for (int t2 = 0; t2 < 4; ++t2) {
            int idx = t2 * 256 + tid;
            int orow = idx >> 4, u = idx & 15;
            *(float4*)&og[(size_t)orow * LSEQ + u * 4] = *(const float4*)&Sf[orow * 68 + u * 4];
        }
        __syncthreads();
    }
}

// ---------------------------------------------------------------------------
extern "C" void kernel_launch(void* const* d_in, const int* in_sizes, int n_in,
                              void* d_out, int out_size, void* d_ws, size_t ws_size,
                              hipStream_t stream)
{
    const float* x       = (const float*)d_in[0];
    const float* xorg    = (const float*)d_in[1];
    const float* abspos  = (const float*)d_in[2];
    const float* mask    = (const float*)d_in[3];
    const float* norm    = (const float*)d_in[4];
    const float* qkpos   = (const float*)d_in[5];
    const float* qkorg   = (const float*)d_in[6];
    const float* vorg    = (const float*)d_in[7];
    const float* relpos  = (const float*)d_in[8];
    const float* gate_w  = (const float*)d_in[9];
    const float* gate_b  = (const float*)d_in[10];
    const float* q_w     = (const float*)d_in[11];
    const float* k_w     = (const float*)d_in[12];
    const float* v_w     = (const float*)d_in[13];
    const float* dense_w = (const float*)d_in[14];
    const float* dense_b = (const float*)d_in[15];
    float* out = (float*)d_out;

    const size_t TEN = (size_t)N_B * CHID * LSEQ * sizeof(bf16);  // 6291456 B
    const size_t WB  = (size_t)CHID * CIO * sizeof(bf16);          // 524288 B
    char* ws = (char*)d_ws;
    bf16*  x1t  = (bf16*)(ws);
    bf16*  x0t  = (bf16*)(ws + TEN);
    bf16*  qb   = (bf16*)(ws + 2 * TEN);
    bf16*  kb   = (bf16*)(ws + 3 * TEN);
    bf16*  vb   = (bf16*)(ws + 4 * TEN);
    bf16*  wqb  = (bf16*)(ws + 5 * TEN);              // wq|wk|wv|wd contiguous
    bf16*  wkb  = (bf16*)(ws + 5 * TEN + WB);
    bf16*  wvb  = (bf16*)(ws + 5 * TEN + 2 * WB);
    bf16*  wdb  = (bf16*)(ws + 5 * TEN + 3 * WB);
    float* gpart = (float*)(ws + 5 * TEN + 4 * WB);
    bf16*  ctxt = x1t;   // x1t dead after qkv

    prep_kernel<<<dim3(CIO / 64, LSEQ / 64, N_B), 256, 0, stream>>>(
        x, xorg, abspos, qkorg, qkpos, vorg, gate_w,
        q_w, k_w, v_w, dense_w, wqb, wkb, wvb, wdb, x1t, x0t, gpart);
    qkv_kernel<<<576, 256, 0, stream>>>(wqb, x1t, x0t, qb, kb, vb);
    attn_kernel<<<768, 256, 0, stream>>>(qb, kb, vb, gpart, gate_b,
                                         mask, norm, relpos, ctxt);
    dense_kernel<<<192, 256, 0, stream>>>(wdb, ctxt, dense_b, out);
}

// Round 12
// 161.527 us; speedup vs baseline: 1.0274x; 1.0274x over previous
//
#include <hip/hip_runtime.h>
#include <hip/hip_bf16.h>

#define N_B   16
#define CIO   512
#define LSEQ  384
#define DH    64
#define NH    8
#define CHID  512
#define ME    384

typedef __hip_bfloat16 bf16;
typedef __attribute__((ext_vector_type(8))) short bf16x8;
typedef __attribute__((ext_vector_type(4))) float f32x4;

#define AS1 __attribute__((address_space(1)))
#define AS3 __attribute__((address_space(3)))

__device__ __forceinline__ unsigned short f2bs(float f) {
    union { bf16 b; unsigned short u; } cv; cv.b = __float2bfloat16(f); return cv.u;
}

// async 16B global->LDS: lds dest = wave-uniform base + lane*16
__device__ __forceinline__ void gload_lds16(const bf16* g, bf16* l) {
    __builtin_amdgcn_global_load_lds((const AS1 unsigned int*)g,
                                     (AS3 unsigned int*)l, 16, 0, 0);
}

// ---------------------------------------------------------------------------
// prep (+ folded wconv): X1/X0 rezero -> bf16 transposed [n][l][c]; gate
// partials into gpart; first 512 flat-id blocks also convert weight chunks.
// (R5 form — scalar gate loop beat the MFMA-gate move (R4) by ~8 us)
// ---------------------------------------------------------------------------
__launch_bounds__(256)
__global__ void prep_kernel(const float* __restrict__ x, const float* __restrict__ xorg,
                            const float* __restrict__ abspos,
                            const float* __restrict__ qkorg, const float* __restrict__ qkpos,
                            const float* __restrict__ vorg,
                            const float* __restrict__ gw,
                            const float* __restrict__ q_w, const float* __restrict__ k_w,
                            const float* __restrict__ v_w, const float* __restrict__ dense_w,
                            bf16* __restrict__ wqb, bf16* __restrict__ wkb,
                            bf16* __restrict__ wvb, bf16* __restrict__ wdb,
                            bf16* __restrict__ x1t, bf16* __restrict__ x0t,
                            float* __restrict__ gpart)
{
    __shared__ bf16 T1[64 * 72], T0[64 * 72];
    __shared__ float Traw[64 * 65];
    __shared__ float gws[NH * 64];
    __shared__ float r0[64], r1[64], r2[64];
    const int tid = threadIdx.x;
    const int cb = blockIdx.x;
    const int c0 = cb * 64;
    const int l0 = blockIdx.y * 64;
    const int n  = blockIdx.z;

    {
        int f = blockIdx.x + 8 * (blockIdx.y + 6 * blockIdx.z);
        if (f < 512) {
            int e = (f * 256 + tid) * 8;
            int which = e >> 18;
            int off = e & ((1 << 18) - 1);
            const float* s = which == 0 ? q_w : which == 1 ? k_w : which == 2 ? v_w : dense_w;
            bf16* d       = which == 0 ? wqb : which == 1 ? wkb : which == 2 ? wvb : wdb;
            float4 f0 = *(const float4*)&s[off];
            float4 f1 = *(const float4*)&s[off + 4];
            unsigned short u[8] = {f2bs(f0.x), f2bs(f0.y), f2bs(f0.z), f2bs(f0.w),
                                   f2bs(f1.x), f2bs(f1.y), f2bs(f1.z), f2bs(f1.w)};
            *(uint4*)&d[off] = *(uint4*)u;
        }
    }

    if (tid < 64) {
        int gidx = (c0 + tid) >> 3;
        r0[tid] = vorg[gidx];
        r1[tid] = qkorg[gidx];
        r2[tid] = qkpos[gidx];
    }
    for (int t = tid; t < NH * 64; t += 256) {
        int h = t >> 6, c = t & 63;
        gws[t] = gw[h * CIO + c0 + c];
    }
    __syncthreads();
    const int l = tid & 63, cs = tid >> 6;
    #pragma unroll
    for (int r = 0; r < 16; r++) {
        int cl = r * 4 + cs;
        size_t gi = ((size_t)n * CIO + c0 + cl) * LSEQ + l0 + l;
        float xv = x[gi], xo = xorg[gi];
        Traw[cl * 65 + l] = xv;
        T0[l * 72 + cl] = __float2bfloat16(xv + r0[cl] * xo);
        T1[l * 72 + cl] = __float2bfloat16(xv + r1[cl] * xo + r2[cl] * abspos[gi]);
    }
    __syncthreads();
    for (int t = tid; t < NH * 64; t += 256) {
        int h = t >> 6, ll = t & 63;
        float s = 0.f;
        #pragma unroll
        for (int c = 0; c < 64; c++) s += gws[h * 64 + c] * Traw[c * 65 + ll];
        gpart[(((size_t)cb * N_B + n) * NH + h) * LSEQ + l0 + ll] = s;
    }
    #pragma unroll
    for (int t = 0; t < 2; t++) {
        int idx = t * 256 + tid;
        int lr = idx >> 3, u = idx & 7;
        size_t go = ((size_t)n * LSEQ + l0 + lr) * CIO + c0 + u * 8;
        *(uint4*)&x1t[go] = *(const uint4*)&T1[lr * 72 + u * 8];
        *(uint4*)&x0t[go] = *(const uint4*)&T0[lr * 72 + u * 8];
    }
}

// ---------------------------------------------------------------------------
// Staged MFMA GEMM for q/k/v — R6/R7 form (best measured). BK=64,
// XOR-swizzled staging (pre-swizzled global source + swizzled reads),
// single-buffered, 2 __syncthreads per K-step. Counted-vmcnt dbuf variants
// (R3 BK=32 syncthreads, R11 BK=32 fenced) measured -6/-4.4 us vs this.
// Grid 576 = 12 ot x 3 lt x 16 n, n = Bid&7 (+8) for XCD L2 locality.
// ot 0..3: q (trans out), 4..7: k (trans out), 8..11: v (natural out).
// ---------------------------------------------------------------------------
__launch_bounds__(256)
__global__ void qkv_kernel(const bf16* __restrict__ wall,
                           const bf16* __restrict__ x1t, const bf16* __restrict__ x0t,
                           bf16* __restrict__ qb, bf16* __restrict__ kb,
                           bf16* __restrict__ vb)
{
    __shared__ __align__(16) char smem[32768];
    bf16* As = (bf16*)smem;             // [128][64], XOR-swizzled
    bf16* Bs = (bf16*)(smem + 16384);   // [128][64], XOR-swizzled
    bf16* S  = (bf16*)smem;             // epilogue [64][136]

    const int tid = threadIdx.x;
    const int lane = tid & 63, w = tid >> 6;
    const int l15 = lane & 15, g = lane >> 4;
    const int Bid = blockIdx.x;
    const int rres = Bid & 7, qq = Bid >> 3;    // 0..71
    const int n = rres + 8 * (qq / 36);
    const int t = qq % 36;
    const int ot = t / 3;          // 0..11
    const int lt = t % 3;
    const int osub = (w & 1) * 64, lsub = (w >> 1) * 64;

    const bf16* Wt = wall + (size_t)(ot * 128) * CIO;
    const bf16* Bt = (ot < 8 ? x1t : x0t) + ((size_t)n * LSEQ + lt * 128) * CIO;

    // staging: tile = 16KB = 1024 x 16B chunks; wave w stages chunks
    // (w*4+j)*64 + lane, j = 0..3, of A and of B. Global col pre-swizzled.
    int crow[4], ccol[4];
    #pragma unroll
    for (int j = 0; j < 4; j++) {
        int c = (w * 4 + j) * 64 + lane;
        crow[j] = c >> 3;
        ccol[j] = ((c & 7) ^ (crow[j] & 7)) * 8;
    }

    f32x4 acc[4][4];
    #pragma unroll
    for (int mt = 0; mt < 4; mt++)
        #pragma unroll
        for (int jt = 0; jt < 4; jt++) acc[mt][jt] = f32x4{0.f, 0.f, 0.f, 0.f};

    const int swl = (l15 & 7);   // read-side swizzle base (row&7 == l15&7)

    for (int it = 0; it < 8; ++it) {
        const int k0 = it * 64;
        #pragma unroll
        for (int j = 0; j < 4; j++) {
            gload_lds16(Wt + (size_t)crow[j] * CIO + k0 + ccol[j], As + (w * 4 + j) * 512);
            gload_lds16(Bt + (size_t)crow[j] * CIO + k0 + ccol[j], Bs + (w * 4 + j) * 512);
        }
        __syncthreads();   // drains vmcnt (global_load_lds) before LDS reads
        #pragma unroll
        for (int kk = 0; kk < 2; kk++) {
            const int cS = ((kk * 4 + g) ^ swl) * 8;
            bf16x8 af[4], bfv[4];
            #pragma unroll
            for (int mt = 0; mt < 4; mt++)
                af[mt] = *(const bf16x8*)&As[(osub + mt * 16 + l15) * 64 + cS];
            #pragma unroll
            for (int jt = 0; jt < 4; jt++)
                bfv[jt] = *(const bf16x8*)&Bs[(lsub + jt * 16 + l15) * 64 + cS];
            #pragma unroll
            for (int mt = 0; mt < 4; mt++)
                #pragma unroll
                for (int jt = 0; jt < 4; jt++)
                    acc[mt][jt] = __builtin_amdgcn_mfma_f32_16x16x32_bf16(af[mt], bfv[jt], acc[mt][jt], 0, 0, 0);
        }
        __syncthreads();   // protect LDS from next iter's staging
    }

    // lane holds C[o = osub+mt*16+4g+r][l = lsub+jt*16+l15]
    if (ot < 8) {
        // q/k: transposed out [n][h][l][d], h = 2*(ot&3) + (o>>6)
        bf16* dstb = (ot < 4) ? qb : kb;
        const int hbase = 2 * (ot & 3);
        #pragma unroll
        for (int lh = 0; lh < 2; ++lh) {
            if ((w >> 1) == lh) {
                #pragma unroll
                for (int mt = 0; mt < 4; mt++)
                    #pragma unroll
                    for (int jt = 0; jt < 4; jt++)
                        #pragma unroll
                        for (int r = 0; r < 4; r++)
                            S[(jt * 16 + l15) * 136 + osub + mt * 16 + 4 * g + r] =
                                __float2bfloat16(acc[mt][jt][r]);
            }
            __syncthreads();
            #pragma unroll
            for (int t2 = 0; t2 < 4; ++t2) {
                int idx = t2 * 256 + tid;          // 0..1023
                int lr = idx >> 4, u = idx & 15;
                int ho = u >> 3, dc = u & 7;
                bf16* dst = dstb + (((size_t)n * NH + hbase + ho) * LSEQ
                                    + lt * 128 + lh * 64 + lr) * DH + dc * 8;
                *(uint4*)dst = *(const uint4*)&S[lr * 136 + u * 8];
            }
            __syncthreads();
        }
    } else {
        // v: natural [n][o][l]
        const int ob = (ot - 8) * 128;
        #pragma unroll
        for (int oh = 0; oh < 2; ++oh) {
            if ((w & 1) == oh) {
                #pragma unroll
                for (int mt = 0; mt < 4; mt++)
                    #pragma unroll
                    for (int jt = 0; jt < 4; jt++)
                        #pragma unroll
                        for (int r = 0; r < 4; r++)
                            S[(mt * 16 + 4 * g + r) * 136 + lsub + jt * 16 + l15] =
                                __float2bfloat16(acc[mt][jt][r]);
            }
            __syncthreads();
            #pragma unroll
            for (int t2 = 0; t2 < 4; ++t2) {
                int idx = t2 * 256 + tid;
                int orr = idx >> 4, u = idx & 15;
                bf16* dst = vb + ((size_t)(n * CHID + ob + oh * 64 + orr)) * LSEQ
                               + lt * 128 + u * 8;
                *(uint4*)dst = *(const uint4*)&S[orr * 136 + u * 8];
            }
            __syncthreads();
        }
    }
}

// ---------------------------------------------------------------------------
// MFMA attention v3 (R7 form — best measured): flash-style over 6 KV-tiles
// of 64, K/V staged via global_load_lds, double-buffered, 1 __syncthreads
// per tile, XOR-swizzled. Online softmax. R8 (2x QBLK) and R10 (counted
// vmcnt) were both neutral -> prefetch covered by inter-block TLP (3/CU).
// ---------------------------------------------------------------------------
#define KVT 64
#define NT  (LSEQ / KVT)

__launch_bounds__(256, 3)
__global__ void attn_kernel(const bf16* __restrict__ qt,
                            const bf16* __restrict__ kt,
                            const bf16* __restrict__ v,
                            const float* __restrict__ gpart,
                            const float* __restrict__ gb,
                            const float* __restrict__ mask,
                            const float* __restrict__ norm,
                            const float* __restrict__ relpos,
                            bf16* __restrict__ ctxt)
{
    __shared__ __align__(16) bf16 Kb[2][KVT * DH];   // 2 x 8KB
    __shared__ __align__(16) bf16 Vb[2][KVT * DH];   // 2 x 8KB
    __shared__ __align__(16) bf16 P[4 * 16 * 64];    // 8KB, wave-private 16x64
    __shared__ float relp_s[2 * ME - 1];
    __shared__ float radd_s[LSEQ];

    const int tid = threadIdx.x;
    const int Bid = blockIdx.x;
    const int rres = Bid & 7, qq = Bid >> 3;
    const int n = rres + 8 * (qq / 48);
    const int rem = qq % 48;
    const int h = rem / 6;
    const int i0 = (rem % 6) * 64;
    const int lane = tid & 63;
    const int w = tid >> 6;
    const int l15 = lane & 15, g = lane >> 4;
    const int m0 = w * 16;

    const size_t nh = (size_t)n * NH + h;
    const bf16* kt_g = kt + nh * LSEQ * DH;                      // [384][64]
    const bf16* vg   = v + ((size_t)n * CHID + h * DH) * LSEQ;   // [64][384]

    {
        const float gbh = gb[h];
        for (int i = tid; i < LSEQ; i += 256) {
            float s = gbh + mask[(size_t)n * LSEQ + i];
            #pragma unroll
            for (int cb = 0; cb < 8; cb++)
                s += gpart[(((size_t)cb * N_B + n) * NH + h) * LSEQ + i];
            radd_s[i] = s;
        }
    }
    for (int i = tid; i < 2 * ME - 1; i += 256) relp_s[i] = relpos[i];

    const bf16* qrow = qt + (nh * LSEQ + i0 + m0 + l15) * DH;
    bf16x8 a0 = *(const bf16x8*)&qrow[8 * g];
    bf16x8 a1 = *(const bf16x8*)&qrow[8 * g + 32];
    const float inv_norm = 1.0f / norm[n];

    // staging: tile = 8KB = 512 x 16B chunks; wave w covers chunks
    // {2w,2w+1}*64+lane. LDS dest is linear; global source is pre-swizzled:
    // chunk c -> row=c>>3, colchunk=(c&7)^(row&7)  (inverse == forward XOR).
    const int c0_ = (2 * w) * 64 + lane;
    const int c1_ = (2 * w + 1) * 64 + lane;
    const int kr0 = c0_ >> 3, kc0 = ((c0_ & 7) ^ (kr0 & 7)) * 8;
    const int kr1 = c1_ >> 3, kc1 = ((c1_ & 7) ^ (kr1 & 7)) * 8;
    const int koff0 = kr0 * DH + kc0, koff1 = kr1 * DH + kc1;
    const int voff0 = kr0 * LSEQ + kc0, voff1 = kr1 * LSEQ + kc1;

    // prologue: stage tile 0 into buf 0
    gload_lds16(kt_g + koff0, &Kb[0][(2 * w) * 512]);
    gload_lds16(kt_g + koff1, &Kb[0][(2 * w + 1) * 512]);
    gload_lds16(vg + voff0, &Vb[0][(2 * w) * 512]);
    gload_lds16(vg + voff1, &Vb[0][(2 * w + 1) * 512]);
    __syncthreads();   // drains vmcnt -> tile0 resident; radd/relp ready

    const int ib = i0 + m0 + 4 * g;
    bf16* Pw = P + w * 1024;      // wave-private [16][64], XOR-swizzled

    f32x4 oacc[4];
    #pragma unroll
    for (int dn = 0; dn < 4; dn++) oacc[dn] = f32x4{0.f, 0.f, 0.f, 0.f};
    float m_r[4]  = {-1e30f, -1e30f, -1e30f, -1e30f};
    float lsum[4] = {0.f, 0.f, 0.f, 0.f};

    #pragma unroll 2
    for (int t = 0; t < NT; ++t) {
        const int cur = t & 1;
        if (t + 1 < NT) {
            const bf16* kn = kt_g + (t + 1) * (KVT * DH);
            const bf16* vn = vg + (t + 1) * KVT;
            gload_lds16(kn + koff0, &Kb[cur ^ 1][(2 * w) * 512]);
            gload_lds16(kn + koff1, &Kb[cur ^ 1][(2 * w + 1) * 512]);
            gload_lds16(vn + voff0, &Vb[cur ^ 1][(2 * w) * 512]);
            gload_lds16(vn + voff1, &Vb[cur ^ 1][(2 * w + 1) * 512]);
        }

        // ---- QK^T on Kb[cur] (swizzled reads, <=2-way banks) ----
        f32x4 acc[4];
        #pragma unroll
        for (int jt = 0; jt < 4; jt++) acc[jt] = f32x4{0.f, 0.f, 0.f, 0.f};
        #pragma unroll
        for (int jt = 0; jt < 4; jt++) {
            const int row = jt * 16 + l15;
            bf16x8 b0 = *(const bf16x8*)&Kb[cur][row * 64 + ((g ^ (row & 7)) * 8)];
            bf16x8 b1 = *(const bf16x8*)&Kb[cur][row * 64 + (((4 + g) ^ (row & 7)) * 8)];
            acc[jt] = __builtin_amdgcn_mfma_f32_16x16x32_bf16(a0, b0, acc[jt], 0, 0, 0);
            acc[jt] = __builtin_amdgcn_mfma_f32_16x16x32_bf16(a1, b1, acc[jt], 0, 0, 0);
        }

        // ---- scores + tile max ----
        float mx[4] = {-1e30f, -1e30f, -1e30f, -1e30f};
        #pragma unroll
        for (int jt = 0; jt < 4; jt++) {
            const int j = t * KVT + jt * 16 + l15;
            const float ra = radd_s[j];
            const int idxb = ME - ib + j;
            #pragma unroll
            for (int r = 0; r < 4; r++) {
                int idx = idxb - r;
                idx = (idx > 2 * ME - 2) ? (2 * ME - 2) : idx;
                float s = (acc[jt][r] + relp_s[idx] + ra) * inv_norm;
                acc[jt][r] = s;
                mx[r] = fmaxf(mx[r], s);
            }
        }
        // ---- online max update + rescale running state ----
        #pragma unroll
        for (int r = 0; r < 4; r++) {
            #pragma unroll
            for (int off = 1; off <= 8; off <<= 1)
                mx[r] = fmaxf(mx[r], __shfl_xor(mx[r], off));
            float mnew = fmaxf(m_r[r], mx[r]);
            float sc = __expf(m_r[r] - mnew);
            m_r[r] = mnew;
            lsum[r] *= sc;
            #pragma unroll
            for (int dn = 0; dn < 4; dn++) oacc[dn][r] *= sc;
        }
        // ---- exp + P write (unscaled; swizzled) ----
        #pragma unroll
        for (int jt = 0; jt < 4; jt++) {
            const int col = jt * 16 + l15;
            #pragma unroll
            for (int r = 0; r < 4; r++) {
                const int lr = 4 * g + r;
                float e = __expf(acc[jt][r] - m_r[r]);
                lsum[r] += e;
                Pw[lr * 64 + (col ^ ((lr & 7) << 3))] = __float2bfloat16(e);
            }
        }

        // ---- PV on Vb[cur] (P is wave-private: lgkmcnt order, no barrier) ----
        #pragma unroll
        for (int kh = 0; kh < 2; kh++) {
            bf16x8 a = *(const bf16x8*)&Pw[l15 * 64 + (((kh * 4 + g) ^ (l15 & 7)) * 8)];
            #pragma unroll
            for (int dn = 0; dn < 4; dn++) {
                const int vr = dn * 16 + l15;
                bf16x8 bv = *(const bf16x8*)&Vb[cur][vr * 64 + (((kh * 4 + g) ^ (vr & 7)) * 8)];
                oacc[dn] = __builtin_amdgcn_mfma_f32_16x16x32_bf16(a, bv, oacc[dn], 0, 0, 0);
            }
        }
        __syncthreads();   // compute(t) done for all waves + drains t+1 stage
    }

    // ---- final denominator + normalize ----
    float rs[4];
    #pragma unroll
    for (int r = 0; r < 4; r++) {
        float tm = lsum[r];
        #pragma unroll
        for (int off = 1; off <= 8; off <<= 1) tm += __shfl_xor(tm, off);
        rs[r] = 1.0f / tm;
    }

    // epilogue: O through Kb (free after last tile barrier), [64][72]
    bf16* O = &Kb[0][0];
    #pragma unroll
    for (int dn = 0; dn < 4; dn++)
        #pragma unroll
        for (int r = 0; r < 4; r++)
            O[(m0 + 4 * g + r) * 72 + dn * 16 + l15] = __float2bfloat16(oacc[dn][r] * rs[r]);
    __syncthreads();

    bf16* cg_ = ctxt + ((size_t)n * LSEQ + i0) * CHID + h * DH;
    #pragma unroll
    for (int t = 0; t < 2; t++) {
        int idx = t * 256 + tid;
        int ir = idx >> 3, u = idx & 7;
        *(uint4*)&cg_[(size_t)ir * CHID + u * 8] = *(const uint4*)&O[ir * 72 + u * 8];
    }
}

// ---------------------------------------------------------------------------
// Dense GEMM: staged 128x128 tile, BK=64, XOR-swizzled global_load_lds.
// (R7 form — the rewrite from direct-global loads was -17 us)
// ---------------------------------------------------------------------------
__launch_bounds__(256)
__global__ void dense_kernel(const bf16* __restrict__ Wb,
                             const bf16* __restrict__ Bt,
                             const float* __restrict__ bias,
                             float* __restrict__ outf)
{
    __shared__ __align__(16) char smem[32768];
    bf16* As = (bf16*)smem;             // [128][64], XOR-swizzled
    bf16* Bs = (bf16*)(smem + 16384);   // [128][64], XOR-swizzled
    float* Sf = (float*)smem;           // epilogue quadrant [64][68] f32

    const int tid = threadIdx.x;
    const int lane = tid & 63, w = tid >> 6;
    const int l15 = lane & 15, g = lane >> 4;
    const int Bid = blockIdx.x;
    const int rres = Bid & 7, qq = Bid >> 3;    // 0..23
    const int n = rres + 8 * (qq / 12);
    const int t = qq % 12;
    const int ot = t / 3;          // 0..3 -> o0 = ot*128
    const int lt = t % 3;          // l0 = lt*128
    const int o0 = ot * 128, l0 = lt * 128;
    const int osub = (w & 1) * 64, lsub = (w >> 1) * 64;

    const bf16* Wt = Wb + (size_t)o0 * CIO;
    const bf16* Btb = Bt + ((size_t)n * LSEQ + l0) * CIO;

    int crow[4], ccol[4];
    #pragma unroll
    for (int j = 0; j < 4; j++) {
        int c = (w * 4 + j) * 64 + lane;
        crow[j] = c >> 3;
        ccol[j] = ((c & 7) ^ (crow[j] & 7)) * 8;
    }

    f32x4 acc[4][4];
    #pragma unroll
    for (int mt = 0; mt < 4; mt++)
        #pragma unroll
        for (int jt = 0; jt < 4; jt++) acc[mt][jt] = f32x4{0.f, 0.f, 0.f, 0.f};

    const int swl = (l15 & 7);

    for (int it = 0; it < 8; ++it) {
        const int k0 = it * 64;
        #pragma unroll
        for (int j = 0; j < 4; j++) {
            gload_lds16(Wt + (size_t)crow[j] * CIO + k0 + ccol[j], As + (w * 4 + j) * 512);
            gload_lds16(Btb + (size_t)crow[j] * CIO + k0 + ccol[j], Bs + (w * 4 + j) * 512);
        }
        __syncthreads();
        #pragma unroll
        for (int kk = 0; kk < 2; kk++) {
            const int cS = ((kk * 4 + g) ^ swl) * 8;
            bf16x8 af[4], bfv[4];
            #pragma unroll
            for (int mt = 0; mt < 4; mt++)
                af[mt] = *(const bf16x8*)&As[(osub + mt * 16 + l15) * 64 + cS];
            #pragma unroll
            for (int jt = 0; jt < 4; jt++)
                bfv[jt] = *(const bf16x8*)&Bs[(lsub + jt * 16 + l15) * 64 + cS];
            #pragma unroll
            for (int mt = 0; mt < 4; mt++)
                #pragma unroll
                for (int jt = 0; jt < 4; jt++)
                    acc[mt][jt] = __builtin_amdgcn_mfma_f32_16x16x32_bf16(af[mt], bfv[jt], acc[mt][jt], 0, 0, 0);
        }
        __syncthreads();
    }

    // epilogue: quadrant (oh,lh) owned by wave p = oh + 2*lh; 4 passes.
    #pragma unroll
    for (int p = 0; p < 4; ++p) {
        const int oh = p & 1, lh = p >> 1;
        if (w == p) {
            #pragma unroll
            for (int mt = 0; mt < 4; mt++) {
                #pragma unroll
                for (int r = 0; r < 4; r++) {
                    const float bv = bias[o0 + osub + mt * 16 + 4 * g + r];
                    #pragma unroll
                    for (int jt = 0; jt < 4; jt++)
                        Sf[(mt * 16 + 4 * g + r) * 68 + jt * 16 + l15] = acc[mt][jt][r] + bv;
                }
            }
        }
        __syncthreads();
        float* og = outf + ((size_t)n * CHID + o0 + oh * 64) * LSEQ + l0 + lh * 64;
        #pragma unroll
        for (int t2 = 0; t2 < 4; ++t2) {
            int idx = t2 * 256 + tid;
            int orow = idx >> 4, u = idx & 15;
            *(float4*)&og[(size_t)orow * LSEQ + u * 4] = *(const float4*)&Sf[orow * 68 + u * 4];
        }
        __syncthreads();
    }
}

// ---------------------------------------------------------------------------
extern "C" void kernel_launch(void* const* d_in, const int* in_sizes, int n_in,
                              void* d_out, int out_size, void* d_ws, size_t ws_size,
                              hipStream_t stream)
{
    const float* x       = (const float*)d_in[0];
    const float* xorg    = (const float*)d_in[1];
    const float* abspos  = (const float*)d_in[2];
    const float* mask    = (const float*)d_in[3];
    const float* norm    = (const float*)d_in[4];
    const float* qkpos   = (const float*)d_in[5];
    const float* qkorg   = (const float*)d_in[6];
    const float* vorg    = (const float*)d_in[7];
    const float* relpos  = (const float*)d_in[8];
    const float* gate_w  = (const float*)d_in[9];
    const float* gate_b  = (const float*)d_in[10];
    const float* q_w     = (const float*)d_in[11];
    const float* k_w     = (const float*)d_in[12];
    const float* v_w     = (const float*)d_in[13];
    const float* dense_w = (const float*)d_in[14];
    const float* dense_b = (const float*)d_in[15];
    float* out = (float*)d_out;

    const size_t TEN = (size_t)N_B * CHID * LSEQ * sizeof(bf16);  // 6291456 B
    const size_t WB  = (size_t)CHID * CIO * sizeof(bf16);          // 524288 B
    char* ws = (char*)d_ws;
    bf16*  x1t  = (bf16*)(ws);
    bf16*  x0t  = (bf16*)(ws + TEN);
    bf16*  qb   = (bf16*)(ws + 2 * TEN);
    bf16*  kb   = (bf16*)(ws + 3 * TEN);
    bf16*  vb   = (bf16*)(ws + 4 * TEN);
    bf16*  wqb  = (bf16*)(ws + 5 * TEN);              // wq|wk|wv|wd contiguous
    bf16*  wkb  = (bf16*)(ws + 5 * TEN + WB);
    bf16*  wvb  = (bf16*)(ws + 5 * TEN + 2 * WB);
    bf16*  wdb  = (bf16*)(ws + 5 * TEN + 3 * WB);
    float* gpart = (float*)(ws + 5 * TEN + 4 * WB);
    bf16*  ctxt = x1t;   // x1t dead after qkv

    prep_kernel<<<dim3(CIO / 64, LSEQ / 64, N_B), 256, 0, stream>>>(
        x, xorg, abspos, qkorg, qkpos, vorg, gate_w,
        q_w, k_w, v_w, dense_w, wqb, wkb, wvb, wdb, x1t, x0t, gpart);
    qkv_kernel<<<576, 256, 0, stream>>>(wqb, x1t, x0t, qb, kb, vb);
    attn_kernel<<<768, 256, 0, stream>>>(qb, kb, vb, gpart, gate_b,
                                         mask, norm, relpos, ctxt);
    dense_kernel<<<192, 256, 0, stream>>>(wdb, ctxt, dense_b, out);
}